// Round 7
// baseline (180.345 us; speedup 1.0000x reference)
//
#include <hip/hip_runtime.h>

#define N_NEURONS 1024
#define TABLE_SIZE 65536
#define BATCH 8192
#define NGROUPS 8            // one neuron-group per XCD (block b -> XCD b%8)
#define NPG 128              // neurons (table rows) per group
#define SPB 256              // samples per block
#define TPB 512              // threads per block (2 threads/sample)
#define NCHUNK 8             // 8 chunks x 16-row window = 128 rows
#define NBLK ((BATCH / SPB) * NGROUPS)   // 256 blocks, 1 per CU
#define BPG (NBLK / NGROUPS)             // 32 blocks per group (one XCD)
#define TS ((size_t)TABLE_SIZE)

// Zero the cross-block barrier counters (8 groups x 32 slots) every launch.
__global__ void qw_init_kernel(unsigned* __restrict__ bar) {
    bar[threadIdx.x] = 0u;
}

// Pass 1: neuron-major partials with CROSS-BLOCK paced 16-row window.
// Block b: group g = b&7 (XCD g via round-robin dispatch), samples
// [(b>>3)*256, +256). Thread t: half h = t&1, sample sid = t>>1.
// Chunk c: ALL 32 blocks of group g gather only rows [g*128+c*16, +16);
// after consuming, blocks arrive at bar[g*32+c] and spin until all 32
// arrived (timeout escape: pacing only, never correctness). A row's 8192
// accesses thus land in one epoch -> ~57% hit the XCD L2 (window 3.6 MB).
__global__ __launch_bounds__(TPB) void qw_partial_kernel(
    const int* __restrict__ data,
    const float* __restrict__ table,
    float* __restrict__ part,           // [NGROUPS][BATCH]
    unsigned* __restrict__ bar)         // [NGROUPS][32]
{
    const int b      = blockIdx.x;
    const int g      = b & (NGROUPS - 1);
    const int sub    = b >> 3;
    const int t      = threadIdx.x;
    const int h      = t & 1;
    const int sid    = t >> 1;                       // 0..255
    const int sample = sub * SPB + sid;

    const int* __restrict__ dptr =
        data + (size_t)sample * N_NEURONS + g * NPG + h * 8;
    const float* __restrict__ tb =
        table + (size_t)(g * NPG + h * 8) * TABLE_SIZE;
    unsigned* __restrict__ gbar = bar + g * 32;

#define IDX(c)  (*reinterpret_cast<const int4*>(dptr + (c) * 16))
#define IDX2(c) (*reinterpret_cast<const int4*>(dptr + (c) * 16 + 4))

    int4 i0 = IDX(0), i1 = IDX2(0);
    float acc = 0.0f;

#pragma unroll
    for (int c = 0; c < NCHUNK; ++c) {
        const int4 c0 = i0;
        const int4 c1 = i1;
        if (c + 1 < NCHUNK) {           // prefetch next chunk's indices
            i0 = IDX(c + 1);
            i1 = IDX2(c + 1);
        }
        const float* __restrict__ tc = tb + (size_t)(c * 16) * TABLE_SIZE;
        const float v0 = tc[(size_t)0 * TS + (size_t)c0.x];
        const float v1 = tc[(size_t)1 * TS + (size_t)c0.y];
        const float v2 = tc[(size_t)2 * TS + (size_t)c0.z];
        const float v3 = tc[(size_t)3 * TS + (size_t)c0.w];
        const float v4 = tc[(size_t)4 * TS + (size_t)c1.x];
        const float v5 = tc[(size_t)5 * TS + (size_t)c1.y];
        const float v6 = tc[(size_t)6 * TS + (size_t)c1.z];
        const float v7 = tc[(size_t)7 * TS + (size_t)c1.w];
        acc += ((v0 + v1) + (v2 + v3)) + ((v4 + v5) + (v6 + v7));

        if (c + 1 < NCHUNK) {
            // cross-block pacing barrier for group g, epoch c
            __syncthreads();            // all waves of this block done with chunk c
            if (t == 0) {
                __hip_atomic_fetch_add(&gbar[c], 1u, __ATOMIC_ACQ_REL,
                                       __HIP_MEMORY_SCOPE_AGENT);
                int budget = 20000;     // timeout escape: pacing only
                while (__hip_atomic_load(&gbar[c], __ATOMIC_ACQUIRE,
                                         __HIP_MEMORY_SCOPE_AGENT) < (unsigned)BPG
                       && --budget) {
                    __builtin_amdgcn_s_sleep(2);
                }
            }
            __syncthreads();            // release the block into chunk c+1
        }
    }
#undef IDX
#undef IDX2

    // combine the two halves of each sample (adjacent lanes)
    acc += __shfl_xor(acc, 1, 64);
    if (h == 0) {
        part[(size_t)g * BATCH + sample] = acc;
    }
}

// Pass 2: out[i] = sum_g part[g][i]
__global__ __launch_bounds__(256) void qw_reduce_kernel(
    const float* __restrict__ part,
    float* __restrict__ out)
{
    const int i = blockIdx.x * 256 + threadIdx.x;
    float s = 0.0f;
#pragma unroll
    for (int g = 0; g < NGROUPS; ++g) {
        s += part[(size_t)g * BATCH + i];
    }
    out[i] = s;
}

// Fallback in case d_ws is too small.
__global__ __launch_bounds__(256) void qw_gather_kernel(
    const int* __restrict__ data,
    const float* __restrict__ table,
    float* __restrict__ out)
{
    const int gtid   = blockIdx.x * blockDim.x + threadIdx.x;
    const int sample = gtid >> 6;
    const int lane   = threadIdx.x & 63;
    if (sample >= BATCH) return;
    const int* __restrict__ row = data + (size_t)sample * N_NEURONS;
    float acc = 0.0f;
#pragma unroll
    for (int k = 0; k < 4; ++k) {
        const int jb = 256 * k + 4 * lane;
        const int4 idx4 = *reinterpret_cast<const int4*>(row + jb);
        acc += table[(size_t)(jb + 0) * TS + idx4.x];
        acc += table[(size_t)(jb + 1) * TS + idx4.y];
        acc += table[(size_t)(jb + 2) * TS + idx4.z];
        acc += table[(size_t)(jb + 3) * TS + idx4.w];
    }
#pragma unroll
    for (int off = 32; off >= 1; off >>= 1) acc += __shfl_xor(acc, off, 64);
    if (lane == 0) out[sample] = acc;
}

extern "C" void kernel_launch(void* const* d_in, const int* in_sizes, int n_in,
                              void* d_out, int out_size, void* d_ws, size_t ws_size,
                              hipStream_t stream)
{
    const int*   data  = (const int*)d_in[0];    // [BATCH, N_NEURONS] int32
    const float* table = (const float*)d_in[1];  // [N_NEURONS, TABLE_SIZE] float32
    float*       out   = (float*)d_out;          // [BATCH] float32

    const size_t part_bytes = (size_t)NGROUPS * BATCH * sizeof(float);   // 256 KB
    const size_t bar_bytes  = (size_t)NGROUPS * 32 * sizeof(unsigned);   // 1 KB
    if (ws_size >= part_bytes + bar_bytes) {
        float*    part = (float*)d_ws;
        unsigned* bar  = (unsigned*)((char*)d_ws + part_bytes);
        qw_init_kernel<<<1, NGROUPS * 32, 0, stream>>>(bar);
        qw_partial_kernel<<<NBLK, TPB, 0, stream>>>(data, table, part, bar);
        qw_reduce_kernel<<<BATCH / 256, 256, 0, stream>>>(part, out);
    } else {
        qw_gather_kernel<<<BATCH / 4, 256, 0, stream>>>(data, table, out);
    }
}

// Round 8
// 105.814 us; speedup vs baseline: 1.7044x; 1.7044x over previous
//
#include <hip/hip_runtime.h>

#define N_NEURONS 1024
#define TABLE_SIZE 65536
#define BATCH 8192
#define NGROUPS 8            // one neuron-group per XCD (block b -> XCD b%8)
#define NPG 128              // neurons (table rows) per group
#define SPB 256              // samples per block
#define TPB 512              // threads per block (2 threads/sample)
#define NCHUNK 8             // 8 chunks x 16-row window = 128 rows
#define NBLK ((BATCH / SPB) * NGROUPS)   // 256 blocks, 1 per CU
#define BPG (NBLK / NGROUPS)             // 32 blocks per group (one XCD)
#define TS ((size_t)TABLE_SIZE)

// Zero the cross-block barrier counters (8 groups x 32 slots) every launch.
__global__ void qw_init_kernel(unsigned* __restrict__ bar) {
    bar[threadIdx.x] = 0u;
}

// Pass 1: neuron-major partials with CROSS-BLOCK paced 16-row window.
// Identical to round 7 EXCEPT the pacing barrier uses RELAXED atomics:
// the flag carries no data, so no ordering (and therefore no L1/L2
// invalidation) is needed. Acquire semantics at agent scope were flushing
// the XCD L2 every epoch crossing -- the exact cache we pace to keep warm.
__global__ __launch_bounds__(TPB) void qw_partial_kernel(
    const int* __restrict__ data,
    const float* __restrict__ table,
    float* __restrict__ part,           // [NGROUPS][BATCH]
    unsigned* __restrict__ bar)         // [NGROUPS][32]
{
    const int b      = blockIdx.x;
    const int g      = b & (NGROUPS - 1);
    const int sub    = b >> 3;
    const int t      = threadIdx.x;
    const int h      = t & 1;
    const int sid    = t >> 1;                       // 0..255
    const int sample = sub * SPB + sid;

    const int* __restrict__ dptr =
        data + (size_t)sample * N_NEURONS + g * NPG + h * 8;
    const float* __restrict__ tb =
        table + (size_t)(g * NPG + h * 8) * TABLE_SIZE;
    unsigned* __restrict__ gbar = bar + g * 32;

#define IDX(c)  (*reinterpret_cast<const int4*>(dptr + (c) * 16))
#define IDX2(c) (*reinterpret_cast<const int4*>(dptr + (c) * 16 + 4))

    int4 i0 = IDX(0), i1 = IDX2(0);
    float acc = 0.0f;

#pragma unroll
    for (int c = 0; c < NCHUNK; ++c) {
        const int4 c0 = i0;
        const int4 c1 = i1;
        if (c + 1 < NCHUNK) {           // prefetch next chunk's indices
            i0 = IDX(c + 1);
            i1 = IDX2(c + 1);
        }
        const float* __restrict__ tc = tb + (size_t)(c * 16) * TABLE_SIZE;
        const float v0 = tc[(size_t)0 * TS + (size_t)c0.x];
        const float v1 = tc[(size_t)1 * TS + (size_t)c0.y];
        const float v2 = tc[(size_t)2 * TS + (size_t)c0.z];
        const float v3 = tc[(size_t)3 * TS + (size_t)c0.w];
        const float v4 = tc[(size_t)4 * TS + (size_t)c1.x];
        const float v5 = tc[(size_t)5 * TS + (size_t)c1.y];
        const float v6 = tc[(size_t)6 * TS + (size_t)c1.z];
        const float v7 = tc[(size_t)7 * TS + (size_t)c1.w];
        acc += ((v0 + v1) + (v2 + v3)) + ((v4 + v5) + (v6 + v7));

        if (c + 1 < NCHUNK) {
            // cross-block pacing barrier for group g, epoch c.
            // RELAXED: pure pacing, no ordering, no cache maintenance.
            __syncthreads();            // all waves of this block done with chunk c
            if (t == 0) {
                __hip_atomic_fetch_add(&gbar[c], 1u, __ATOMIC_RELAXED,
                                       __HIP_MEMORY_SCOPE_AGENT);
                int budget = 30000;     // timeout escape: pacing only
                while (__hip_atomic_load(&gbar[c], __ATOMIC_RELAXED,
                                         __HIP_MEMORY_SCOPE_AGENT) < (unsigned)BPG
                       && --budget) {
                    __builtin_amdgcn_s_sleep(1);
                }
            }
            __syncthreads();            // release the block into chunk c+1
        }
    }
#undef IDX
#undef IDX2

    // combine the two halves of each sample (adjacent lanes)
    acc += __shfl_xor(acc, 1, 64);
    if (h == 0) {
        part[(size_t)g * BATCH + sample] = acc;
    }
}

// Pass 2: out[i] = sum_g part[g][i]
__global__ __launch_bounds__(256) void qw_reduce_kernel(
    const float* __restrict__ part,
    float* __restrict__ out)
{
    const int i = blockIdx.x * 256 + threadIdx.x;
    float s = 0.0f;
#pragma unroll
    for (int g = 0; g < NGROUPS; ++g) {
        s += part[(size_t)g * BATCH + i];
    }
    out[i] = s;
}

// Fallback in case d_ws is too small.
__global__ __launch_bounds__(256) void qw_gather_kernel(
    const int* __restrict__ data,
    const float* __restrict__ table,
    float* __restrict__ out)
{
    const int gtid   = blockIdx.x * blockDim.x + threadIdx.x;
    const int sample = gtid >> 6;
    const int lane   = threadIdx.x & 63;
    if (sample >= BATCH) return;
    const int* __restrict__ row = data + (size_t)sample * N_NEURONS;
    float acc = 0.0f;
#pragma unroll
    for (int k = 0; k < 4; ++k) {
        const int jb = 256 * k + 4 * lane;
        const int4 idx4 = *reinterpret_cast<const int4*>(row + jb);
        acc += table[(size_t)(jb + 0) * TS + idx4.x];
        acc += table[(size_t)(jb + 1) * TS + idx4.y];
        acc += table[(size_t)(jb + 2) * TS + idx4.z];
        acc += table[(size_t)(jb + 3) * TS + idx4.w];
    }
#pragma unroll
    for (int off = 32; off >= 1; off >>= 1) acc += __shfl_xor(acc, off, 64);
    if (lane == 0) out[sample] = acc;
}

extern "C" void kernel_launch(void* const* d_in, const int* in_sizes, int n_in,
                              void* d_out, int out_size, void* d_ws, size_t ws_size,
                              hipStream_t stream)
{
    const int*   data  = (const int*)d_in[0];    // [BATCH, N_NEURONS] int32
    const float* table = (const float*)d_in[1];  // [N_NEURONS, TABLE_SIZE] float32
    float*       out   = (float*)d_out;          // [BATCH] float32

    const size_t part_bytes = (size_t)NGROUPS * BATCH * sizeof(float);   // 256 KB
    const size_t bar_bytes  = (size_t)NGROUPS * 32 * sizeof(unsigned);   // 1 KB
    if (ws_size >= part_bytes + bar_bytes) {
        float*    part = (float*)d_ws;
        unsigned* bar  = (unsigned*)((char*)d_ws + part_bytes);
        qw_init_kernel<<<1, NGROUPS * 32, 0, stream>>>(bar);
        qw_partial_kernel<<<NBLK, TPB, 0, stream>>>(data, table, part, bar);
        qw_reduce_kernel<<<BATCH / 256, 256, 0, stream>>>(part, out);
    } else {
        qw_gather_kernel<<<BATCH / 4, 256, 0, stream>>>(data, table, out);
    }
}

// Round 9
// 104.640 us; speedup vs baseline: 1.7235x; 1.0112x over previous
//
#include <hip/hip_runtime.h>

#define N_NEURONS 1024
#define TABLE_SIZE 65536
#define BATCH 8192
#define NGROUPS 8            // one neuron-group per XCD (block b -> XCD b%8)
#define NPG 128              // neurons (table rows) per group
#define SPB 256              // samples per block
#define TPB 512              // threads per block (2 threads/sample)
#define NCHUNK 8             // 8 chunks x 16-row window = 128 rows
#define NBLK ((BATCH / SPB) * NGROUPS)   // 256 blocks, 1 per CU
#define BPG (NBLK / NGROUPS)             // 32 blocks per group (one XCD)
#define TS ((size_t)TABLE_SIZE)

// Zero the cross-block barrier counters (8 groups x 32 slots) every launch.
__global__ void qw_init_kernel(unsigned* __restrict__ bar) {
    bar[threadIdx.x] = 0u;
}

// Pass 1: neuron-major partials, cross-block paced window, PIPELINED ACROSS
// THE BARRIER. Per epoch c: issue chunk c+1's gathers + prefetch idx c+2,
// THEN arrive/spin at the relaxed pacing barrier (chunk c+1 stays in flight
// through the wait -- raw s_barrier, no vmcnt drain), then consume chunk c.
// Pacing keeps the group's sweep within ~2 chunks (32 rows ~ 7.3 MB), which
// is LLC-resident; warm replays serve everything from cache (R7: ~0 HBM).
__global__ __launch_bounds__(TPB) void qw_partial_kernel(
    const int* __restrict__ data,
    const float* __restrict__ table,
    float* __restrict__ part,           // [NGROUPS][BATCH]
    unsigned* __restrict__ bar)         // [NGROUPS][32]
{
    const int b      = blockIdx.x;
    const int g      = b & (NGROUPS - 1);
    const int sub    = b >> 3;
    const int t      = threadIdx.x;
    const int h      = t & 1;
    const int sid    = t >> 1;                       // 0..255
    const int sample = sub * SPB + sid;

    const int* __restrict__ dptr =
        data + (size_t)sample * N_NEURONS + g * NPG + h * 8;
    const float* __restrict__ tb =
        table + (size_t)(g * NPG + h * 8) * TABLE_SIZE;
    unsigned* __restrict__ gbar = bar + g * 32;

#define IDX(c)  (*reinterpret_cast<const int4*>(dptr + (c) * 16))
#define IDX2(c) (*reinterpret_cast<const int4*>(dptr + (c) * 16 + 4))

#define GATHER(d0,d1,d2,d3,d4,d5,d6,d7, c, I0, I1)                    \
    d0 = tb[((size_t)(c) * 16 + 0) * TS + (size_t)(I0).x];            \
    d1 = tb[((size_t)(c) * 16 + 1) * TS + (size_t)(I0).y];            \
    d2 = tb[((size_t)(c) * 16 + 2) * TS + (size_t)(I0).z];            \
    d3 = tb[((size_t)(c) * 16 + 3) * TS + (size_t)(I0).w];            \
    d4 = tb[((size_t)(c) * 16 + 4) * TS + (size_t)(I1).x];            \
    d5 = tb[((size_t)(c) * 16 + 5) * TS + (size_t)(I1).y];            \
    d6 = tb[((size_t)(c) * 16 + 6) * TS + (size_t)(I1).z];            \
    d7 = tb[((size_t)(c) * 16 + 7) * TS + (size_t)(I1).w];

#define SUM8(d0,d1,d2,d3,d4,d5,d6,d7) \
    (((d0 + d1) + (d2 + d3)) + ((d4 + d5) + (d6 + d7)))

    // Pacing barrier for epoch c. Issue-before / consume-after; the memory
    // clobbers pin the issue order at compile time; raw s_barrier does NOT
    // drain vmcnt, so the just-issued chunk rides through the wait.
    // RELAXED atomics: pure pacing flag, no ordering, no cache maintenance.
    // Timeout escape: pacing only, never correctness.
#define PACE(c)                                                            \
    asm volatile("" ::: "memory");                                         \
    __builtin_amdgcn_s_barrier();                                          \
    if (t == 0) {                                                          \
        __hip_atomic_fetch_add(&gbar[c], 1u, __ATOMIC_RELAXED,             \
                               __HIP_MEMORY_SCOPE_AGENT);                  \
        int budget = 20000;                                                \
        while (__hip_atomic_load(&gbar[c], __ATOMIC_RELAXED,               \
                                 __HIP_MEMORY_SCOPE_AGENT) < (unsigned)BPG \
               && --budget) {                                              \
            __builtin_amdgcn_s_sleep(1);                                   \
        }                                                                  \
    }                                                                      \
    __builtin_amdgcn_s_barrier();                                          \
    asm volatile("" ::: "memory");

    int4 p0 = IDX(0), p1 = IDX2(0);
    float A0,A1,A2,A3,A4,A5,A6,A7;
    float B0,B1,B2,B3,B4,B5,B6,B7;
    float acc = 0.0f;

    // prologue: chunk 0 in flight
    GATHER(A0,A1,A2,A3,A4,A5,A6,A7, 0, p0, p1);
    int4 q0 = IDX(1), q1 = IDX2(1);

    // epoch 0: issue chunk1, prefetch idx2, pace, consume chunk0
    GATHER(B0,B1,B2,B3,B4,B5,B6,B7, 1, q0, q1);
    p0 = IDX(2); p1 = IDX2(2);
    PACE(0);
    acc += SUM8(A0,A1,A2,A3,A4,A5,A6,A7);

    // epoch 1: issue chunk2, prefetch idx3, pace, consume chunk1
    GATHER(A0,A1,A2,A3,A4,A5,A6,A7, 2, p0, p1);
    q0 = IDX(3); q1 = IDX2(3);
    PACE(1);
    acc += SUM8(B0,B1,B2,B3,B4,B5,B6,B7);

    // epoch 2: issue chunk3, prefetch idx4, pace, consume chunk2
    GATHER(B0,B1,B2,B3,B4,B5,B6,B7, 3, q0, q1);
    p0 = IDX(4); p1 = IDX2(4);
    PACE(2);
    acc += SUM8(A0,A1,A2,A3,A4,A5,A6,A7);

    // epoch 3: issue chunk4, prefetch idx5, pace, consume chunk3
    GATHER(A0,A1,A2,A3,A4,A5,A6,A7, 4, p0, p1);
    q0 = IDX(5); q1 = IDX2(5);
    PACE(3);
    acc += SUM8(B0,B1,B2,B3,B4,B5,B6,B7);

    // epoch 4: issue chunk5, prefetch idx6, pace, consume chunk4
    GATHER(B0,B1,B2,B3,B4,B5,B6,B7, 5, q0, q1);
    p0 = IDX(6); p1 = IDX2(6);
    PACE(4);
    acc += SUM8(A0,A1,A2,A3,A4,A5,A6,A7);

    // epoch 5: issue chunk6, prefetch idx7, pace, consume chunk5
    GATHER(A0,A1,A2,A3,A4,A5,A6,A7, 6, p0, p1);
    q0 = IDX(7); q1 = IDX2(7);
    PACE(5);
    acc += SUM8(B0,B1,B2,B3,B4,B5,B6,B7);

    // epoch 6: issue chunk7, pace, consume chunk6
    GATHER(B0,B1,B2,B3,B4,B5,B6,B7, 7, q0, q1);
    PACE(6);
    acc += SUM8(A0,A1,A2,A3,A4,A5,A6,A7);

    // tail: consume chunk7
    acc += SUM8(B0,B1,B2,B3,B4,B5,B6,B7);

#undef PACE
#undef GATHER
#undef SUM8
#undef IDX
#undef IDX2

    // combine the two halves of each sample (adjacent lanes)
    acc += __shfl_xor(acc, 1, 64);
    if (h == 0) {
        part[(size_t)g * BATCH + sample] = acc;
    }
}

// Pass 2: out[i] = sum_g part[g][i]
__global__ __launch_bounds__(256) void qw_reduce_kernel(
    const float* __restrict__ part,
    float* __restrict__ out)
{
    const int i = blockIdx.x * 256 + threadIdx.x;
    float s = 0.0f;
#pragma unroll
    for (int g = 0; g < NGROUPS; ++g) {
        s += part[(size_t)g * BATCH + i];
    }
    out[i] = s;
}

// Fallback in case d_ws is too small.
__global__ __launch_bounds__(256) void qw_gather_kernel(
    const int* __restrict__ data,
    const float* __restrict__ table,
    float* __restrict__ out)
{
    const int gtid   = blockIdx.x * blockDim.x + threadIdx.x;
    const int sample = gtid >> 6;
    const int lane   = threadIdx.x & 63;
    if (sample >= BATCH) return;
    const int* __restrict__ row = data + (size_t)sample * N_NEURONS;
    float acc = 0.0f;
#pragma unroll
    for (int k = 0; k < 4; ++k) {
        const int jb = 256 * k + 4 * lane;
        const int4 idx4 = *reinterpret_cast<const int4*>(row + jb);
        acc += table[(size_t)(jb + 0) * TS + idx4.x];
        acc += table[(size_t)(jb + 1) * TS + idx4.y];
        acc += table[(size_t)(jb + 2) * TS + idx4.z];
        acc += table[(size_t)(jb + 3) * TS + idx4.w];
    }
#pragma unroll
    for (int off = 32; off >= 1; off >>= 1) acc += __shfl_xor(acc, off, 64);
    if (lane == 0) out[sample] = acc;
}

extern "C" void kernel_launch(void* const* d_in, const int* in_sizes, int n_in,
                              void* d_out, int out_size, void* d_ws, size_t ws_size,
                              hipStream_t stream)
{
    const int*   data  = (const int*)d_in[0];    // [BATCH, N_NEURONS] int32
    const float* table = (const float*)d_in[1];  // [N_NEURONS, TABLE_SIZE] float32
    float*       out   = (float*)d_out;          // [BATCH] float32

    const size_t part_bytes = (size_t)NGROUPS * BATCH * sizeof(float);   // 256 KB
    const size_t bar_bytes  = (size_t)NGROUPS * 32 * sizeof(unsigned);   // 1 KB
    if (ws_size >= part_bytes + bar_bytes) {
        float*    part = (float*)d_ws;
        unsigned* bar  = (unsigned*)((char*)d_ws + part_bytes);
        qw_init_kernel<<<1, NGROUPS * 32, 0, stream>>>(bar);
        qw_partial_kernel<<<NBLK, TPB, 0, stream>>>(data, table, part, bar);
        qw_reduce_kernel<<<BATCH / 256, 256, 0, stream>>>(part, out);
    } else {
        qw_gather_kernel<<<BATCH / 4, 256, 0, stream>>>(data, table, out);
    }
}

// Round 10
// 101.630 us; speedup vs baseline: 1.7745x; 1.0296x over previous
//
#include <hip/hip_runtime.h>

#define N_NEURONS 1024
#define TABLE_SIZE 65536
#define BATCH 8192
#define NGROUPS 8            // one neuron-group per XCD (block b -> XCD b%8)
#define NPG 128              // neurons (table rows) per group
#define SPB 128              // samples per block
#define TPB 256              // threads per block (2 threads/sample)
#define NPHASE 8             // 8 phases x 16-row window = 128 rows/group
#define NBLK ((BATCH / SPB) * NGROUPS)   // 512 blocks, 2 per CU
#define TS ((size_t)TABLE_SIZE)

// Phase p: every block gathers ONLY rows [g*128 + p*16, +16) of its group.
// Stream-ordered launches are the pacing barrier: HW-enforced, no spin, no
// atomics, no fences. Per XCD the live window is 16 rows ~ 3.6 MB < 4 MiB L2
// (R7 measured this exact window at 169 MB total FETCH vs 530 MB unpaced).
// part[g][sample] accumulates across phases: '=' on phase 0 (fully
// overwrites poisoned ws), '+=' afterwards -- deterministic every call.
__global__ __launch_bounds__(TPB) void qw_phase_kernel(
    const int* __restrict__ data,
    const float* __restrict__ table,
    float* __restrict__ part,           // [NGROUPS][BATCH]
    int phase)
{
    const int b      = blockIdx.x;
    const int g      = b & (NGROUPS - 1);
    const int sub    = b >> 3;
    const int t      = threadIdx.x;
    const int h      = t & 1;
    const int sid    = t >> 1;                       // 0..127
    const int sample = sub * SPB + sid;

    const int jbase  = g * NPG + phase * 16 + h * 8; // this thread's 8 rows

    // One 64-B idx line per sample per phase, split between the two threads
    // (h=0 first 32 B, h=1 second 32 B) -> fully consumed, no over-fetch.
    const int* __restrict__ dptr = data + (size_t)sample * N_NEURONS + jbase;
    const int4 i0 = *reinterpret_cast<const int4*>(dptr);
    const int4 i1 = *reinterpret_cast<const int4*>(dptr + 4);

    const float* __restrict__ tb = table + (size_t)jbase * TABLE_SIZE;

    // 8 independent gathers, all within the XCD's 16-row L2-resident window
    const float v0 = tb[(size_t)0 * TS + (size_t)i0.x];
    const float v1 = tb[(size_t)1 * TS + (size_t)i0.y];
    const float v2 = tb[(size_t)2 * TS + (size_t)i0.z];
    const float v3 = tb[(size_t)3 * TS + (size_t)i0.w];
    const float v4 = tb[(size_t)4 * TS + (size_t)i1.x];
    const float v5 = tb[(size_t)5 * TS + (size_t)i1.y];
    const float v6 = tb[(size_t)6 * TS + (size_t)i1.z];
    const float v7 = tb[(size_t)7 * TS + (size_t)i1.w];
    float acc = ((v0 + v1) + (v2 + v3)) + ((v4 + v5) + (v6 + v7));

    // combine the two halves of each sample (adjacent lanes)
    acc += __shfl_xor(acc, 1, 64);

    if (h == 0) {
        float* dst = part + (size_t)g * BATCH + sample;
        if (phase == 0) {
            *dst = acc;                 // overwrite poisoned workspace
        } else {
            *dst += acc;                // stream-ordered RMW, race-free
        }
    }
}

// Final: out[i] = sum_g part[g][i]
__global__ __launch_bounds__(256) void qw_reduce_kernel(
    const float* __restrict__ part,
    float* __restrict__ out)
{
    const int i = blockIdx.x * 256 + threadIdx.x;
    float s = 0.0f;
#pragma unroll
    for (int g = 0; g < NGROUPS; ++g) {
        s += part[(size_t)g * BATCH + i];
    }
    out[i] = s;
}

// Fallback in case d_ws is too small (R6 chassis, 84 us standalone).
__global__ __launch_bounds__(256) void qw_gather_kernel(
    const int* __restrict__ data,
    const float* __restrict__ table,
    float* __restrict__ out)
{
    const int gtid   = blockIdx.x * blockDim.x + threadIdx.x;
    const int sample = gtid >> 6;
    const int lane   = threadIdx.x & 63;
    if (sample >= BATCH) return;
    const int* __restrict__ row = data + (size_t)sample * N_NEURONS;
    float acc = 0.0f;
#pragma unroll
    for (int k = 0; k < 4; ++k) {
        const int jb = 256 * k + 4 * lane;
        const int4 idx4 = *reinterpret_cast<const int4*>(row + jb);
        acc += table[(size_t)(jb + 0) * TS + idx4.x];
        acc += table[(size_t)(jb + 1) * TS + idx4.y];
        acc += table[(size_t)(jb + 2) * TS + idx4.z];
        acc += table[(size_t)(jb + 3) * TS + idx4.w];
    }
#pragma unroll
    for (int off = 32; off >= 1; off >>= 1) acc += __shfl_xor(acc, off, 64);
    if (lane == 0) out[sample] = acc;
}

extern "C" void kernel_launch(void* const* d_in, const int* in_sizes, int n_in,
                              void* d_out, int out_size, void* d_ws, size_t ws_size,
                              hipStream_t stream)
{
    const int*   data  = (const int*)d_in[0];    // [BATCH, N_NEURONS] int32
    const float* table = (const float*)d_in[1];  // [N_NEURONS, TABLE_SIZE] float32
    float*       out   = (float*)d_out;          // [BATCH] float32

    const size_t part_bytes = (size_t)NGROUPS * BATCH * sizeof(float);   // 256 KB
    if (ws_size >= part_bytes) {
        float* part = (float*)d_ws;
        for (int p = 0; p < NPHASE; ++p) {
            qw_phase_kernel<<<NBLK, TPB, 0, stream>>>(data, table, part, p);
        }
        qw_reduce_kernel<<<BATCH / 256, 256, 0, stream>>>(part, out);
    } else {
        qw_gather_kernel<<<BATCH / 4, 256, 0, stream>>>(data, table, out);
    }
}